// Round 4
// baseline (430.266 us; speedup 1.0000x reference)
//
#include <hip/hip_runtime.h>

typedef float v4f __attribute__((ext_vector_type(4)));

#define B_     64
#define CIN    64
#define CO     16
#define NN     307
#define LL     12
#define JT     (NN * LL)   // 3684
#define LHP    320         // padded lhat row stride
#define CHUNK  256         // jt columns per strip block
#define NCHUNK 15          // ceil(3684/256)
#define NRG    20          // ceil(307/16) row-groups

// ---------------------------------------------------------------------------
// Kernel 0: repack w [o][i][k] -> wt [i][k][o] (wave-uniform 16-float rows).
// ---------------------------------------------------------------------------
__global__ void repack_w_kernel(const float* __restrict__ w, float* __restrict__ wt) {
    int t = blockIdx.x * 256 + threadIdx.x;
    if (t < CO * CIN * 3) {
        int o = t & 15;
        int k = (t >> 4) % 3;
        int i = t / 48;
        wt[i * 48 + k * 16 + o] = w[(o * CIN + i) * 3 + k];
    }
}

// ---------------------------------------------------------------------------
// Kernel 1: lhat[b][c][n] = normalized conv output at l = 11 (last timestep).
// One thread per (b,n). Taps: l-1 and l only (l+1 is out of range at l=11).
// ---------------------------------------------------------------------------
__global__ __launch_bounds__(256) void lhat_kernel(
    const float* __restrict__ x, const float* __restrict__ wt,
    const float* __restrict__ bias, float* __restrict__ lhat) {
    int tid = blockIdx.x * 256 + threadIdx.x;
    if (tid >= B_ * NN) return;
    int b = tid / NN, n = tid - b * NN;
    const float* xp = x + (size_t)b * CIN * JT + n * LL + (LL - 1);

    float acc[CO];
#pragma unroll
    for (int o = 0; o < CO; ++o) acc[o] = bias[o];

#pragma unroll 4
    for (int i = 0; i < CIN; ++i) {
        float xm = xp[i * JT - 1];
        float x0 = xp[i * JT];
        const float* wr = wt + i * 48;   // wave-uniform -> s_load
#pragma unroll
        for (int o = 0; o < CO; ++o)
            acc[o] += wr[o] * xm + wr[16 + o] * x0;
    }

    float ss = 0.f;
#pragma unroll
    for (int o = 0; o < CO; ++o) ss += acc[o] * acc[o];
    float inv = 1.f / fmaxf(sqrtf(ss), 1e-8f);

    float* lp = lhat + (size_t)b * CO * LHP + n;
#pragma unroll
    for (int o = 0; o < CO; ++o) lp[o * LHP] = acc[o] * inv;   // coalesced in n
}

// ---------------------------------------------------------------------------
// Kernel 2 (fused): per (b, jt-chunk of 256):
//   phase A: each thread conv+norm's its OWN jt column (16 ch in regs),
//            writes the 16x256 yhat tile to LDS (16 KB).
//   phase B: hoist tile to 16 v4f registers/thread, then 20 row-groups of
//            pure-register FMA; lhat via wave-uniform loads; stores are
//            wave-contiguous 1 KB per instruction (cached, no NT).
// No global yhat tensor -> no cross-XCD L3 latency in the hot loop.
// ---------------------------------------------------------------------------
__global__ __launch_bounds__(256) void strip_kernel(
    const float* __restrict__ x, const float* __restrict__ wt,
    const float* __restrict__ bias, const float* __restrict__ lhat,
    float* __restrict__ out) {
    __shared__ float ylds[CO][CHUNK];   // 16 KB

    const int b   = blockIdx.y;
    const int jt0 = blockIdx.x * CHUNK;
    const int t   = threadIdx.x;

    // ---- phase A: conv + norm for column jt0+t ----
    int jt  = jt0 + t;
    int jtc = (jt < JT) ? jt : (JT - 1);   // clamp: finite garbage, masked later
    int n   = jtc / LL;
    int l   = jtc - n * LL;

    const float* xp = x + (size_t)b * CIN * JT + jtc;

    float acc[CO];
#pragma unroll
    for (int o = 0; o < CO; ++o) acc[o] = bias[o];

    const int   offm = (l > 0) ? -1 : 0;
    const int   offp = (l < LL - 1) ? 1 : 0;
    const float mm   = (l > 0) ? 1.f : 0.f;
    const float mp   = (l < LL - 1) ? 1.f : 0.f;

#pragma unroll 4
    for (int i = 0; i < CIN; ++i) {
        const float* xr = xp + i * JT;
        float xm = xr[offm] * mm;
        float x0 = xr[0];
        float xq = xr[offp] * mp;
        const float* wr = wt + i * 48;   // wave-uniform -> s_load
#pragma unroll
        for (int o = 0; o < CO; ++o)
            acc[o] += wr[o] * xm + wr[16 + o] * x0 + wr[32 + o] * xq;
    }

    float ss = 0.f;
#pragma unroll
    for (int o = 0; o < CO; ++o) ss += acc[o] * acc[o];
    float inv = 1.f / fmaxf(sqrtf(ss), 1e-8f);

#pragma unroll
    for (int o = 0; o < CO; ++o) ylds[o][t] = acc[o] * inv;   // conflict-free

    __syncthreads();

    // ---- phase B: rank-16 GEMM from registers ----
    const int lane = t & 63;
    const int wv   = t >> 6;
    const int jtA  = jt0 + lane * 4;
    const bool vA  = (jtA < JT);        // JT % 4 == 0: whole-float4 validity

    v4f y[CO];                          // 64 VGPR: the tile slice, read once
#pragma unroll
    for (int c = 0; c < CO; ++c) y[c] = *(const v4f*)&ylds[c][lane * 4];

    const float* lb = lhat + (size_t)b * CO * LHP;
    float* ob = out + (size_t)b * NN * JT + jtA;

    for (int rg = 0; rg < NRG; ++rg) {
        const int ib = rg * 16 + wv * 4;
        const float* lp = lb + ib;      // wave-uniform -> scalar loads

        v4f a0 = (v4f)0.f, a1 = (v4f)0.f, a2 = (v4f)0.f, a3 = (v4f)0.f;
#pragma unroll
        for (int c = 0; c < CO; ++c) {
            v4f lt = *(const v4f*)(lp + c * LHP);
            a0 += lt[0] * y[c];
            a1 += lt[1] * y[c];
            a2 += lt[2] * y[c];
            a3 += lt[3] * y[c];
        }

        if (vA) {
            if (ib + 0 < NN) *(v4f*)(ob + (size_t)(ib + 0) * JT) = a0;
            if (ib + 1 < NN) *(v4f*)(ob + (size_t)(ib + 1) * JT) = a1;
            if (ib + 2 < NN) *(v4f*)(ob + (size_t)(ib + 2) * JT) = a2;
            if (ib + 3 < NN) *(v4f*)(ob + (size_t)(ib + 3) * JT) = a3;
        }
    }
}

extern "C" void kernel_launch(void* const* d_in, const int* in_sizes, int n_in,
                              void* d_out, int out_size, void* d_ws, size_t ws_size,
                              hipStream_t stream) {
    const float* x    = (const float*)d_in[0];
    const float* w    = (const float*)d_in[1];
    const float* bias = (const float*)d_in[2];
    float* out = (float*)d_out;

    float* ws   = (float*)d_ws;
    float* lhat = ws;                               // B_*CO*LHP = 327,680 f
    float* wt   = lhat + (size_t)B_ * CO * LHP;     // 3072 f  (~1.3 MB total)

    repack_w_kernel<<<(CO * CIN * 3 + 255) / 256, 256, 0, stream>>>(w, wt);

    lhat_kernel<<<(B_ * NN + 255) / 256, 256, 0, stream>>>(x, wt, bias, lhat);

    dim3 g(NCHUNK, B_);
    strip_kernel<<<g, 256, 0, stream>>>(x, wt, bias, lhat, out);
}

// Round 5
// 419.620 us; speedup vs baseline: 1.0254x; 1.0254x over previous
//
#include <hip/hip_runtime.h>

typedef float v4f __attribute__((ext_vector_type(4)));

#define B_   64
#define CIN  64
#define CO   16
#define NN   307
#define LL   12
#define JT   (NN * LL)   // 3684
#define LHP  320         // padded lhat row stride (16B-aligned float4 rows)

// cos grid: 20 i-groups x 4 jt-groups x 64 b = 5120 blocks, XCD-swizzled
#define NIG  20
#define NJTG 4
#define NWG  (NIG * NJTG * B_)       // 5120
#define WPX  (NWG / 8)               // 640 per XCD

// ---------------------------------------------------------------------------
// Kernel 0: repack w [o][i][k] -> wt [i][k][o] (wave-uniform 16-float rows).
// ---------------------------------------------------------------------------
__global__ void repack_w_kernel(const float* __restrict__ w, float* __restrict__ wt) {
    int t = blockIdx.x * 256 + threadIdx.x;
    if (t < CO * CIN * 3) {
        int o = t & 15;
        int k = (t >> 4) % 3;
        int i = t / 48;
        wt[i * 48 + k * 16 + o] = w[(o * CIN + i) * 3 + k];
    }
}

// ---------------------------------------------------------------------------
// Kernel 1: conv(1x3, pad 1) + bias + channel-norm fold (round-2 proven form).
// One thread per (b,n,l); weights via wave-uniform (scalar) loads.
// Writes yhat[b][c][n][l] and the l==11 slice into lhat[b][c][n] (LHP pad).
// ---------------------------------------------------------------------------
__global__ __launch_bounds__(256) void conv_norm_kernel(
    const float* __restrict__ x, const float* __restrict__ wt,
    const float* __restrict__ bias, float* __restrict__ yhat,
    float* __restrict__ lhat) {
    int tid = blockIdx.x * 256 + threadIdx.x;   // exactly B_*JT threads
    int b   = tid / JT;
    int rem = tid - b * JT;                     // n*12 + l
    int n   = rem / LL;
    int l   = rem - n * LL;

    const float* xp = x + (size_t)b * CIN * JT + rem;

    float acc[CO];
#pragma unroll
    for (int o = 0; o < CO; ++o) acc[o] = bias[o];

    const int   offm = (l > 0) ? -1 : 0;
    const int   offp = (l < LL - 1) ? 1 : 0;
    const float mm   = (l > 0) ? 1.f : 0.f;
    const float mp   = (l < LL - 1) ? 1.f : 0.f;

#pragma unroll 4
    for (int i = 0; i < CIN; ++i) {
        const float* xr = xp + i * JT;
        float xm = xr[offm] * mm;
        float x0 = xr[0];
        float xq = xr[offp] * mp;
        const float* wr = wt + i * 48;   // wave-uniform -> s_load
#pragma unroll
        for (int o = 0; o < CO; ++o) {
            acc[o] += wr[o] * xm + wr[16 + o] * x0 + wr[32 + o] * xq;
        }
    }

    float ss = 0.f;
#pragma unroll
    for (int o = 0; o < CO; ++o) ss += acc[o] * acc[o];
    float inv = 1.f / fmaxf(sqrtf(ss), 1e-8f);

    float* yp = yhat + (size_t)b * CO * JT + rem;
#pragma unroll
    for (int o = 0; o < CO; ++o) yp[o * JT] = acc[o] * inv;

    if (l == LL - 1) {
        float* lp = lhat + (size_t)b * CO * LHP + n;
#pragma unroll
        for (int o = 0; o < CO; ++o) lp[o * LHP] = acc[o] * inv;
    }
}

// ---------------------------------------------------------------------------
// Kernel 2: out[b][i][jt] = sum_c lhat[b][c][i] * yhat[b][c][jt]
// Retiled for store sequentiality + XCD L2 locality:
//   block = 16 i x 1024 jt; wave = 4 rows, 4 adjacent 1KB spans per row ->
//   4KB sequential stores per row per wave (closer to the fill's pattern).
//   XCD-bijective swizzle: XCD k owns batches [8k, 8k+8) entirely, so the
//   80 blocks sharing a 236KB yhat b-slice re-read it from the local L2.
// ---------------------------------------------------------------------------
__global__ __launch_bounds__(256) void cos_kernel(
    const float* __restrict__ yhat, const float* __restrict__ lhat,
    float* __restrict__ out) {
    // bijective XCD remap (NWG % 8 == 0): lin%8 = hw XCD round-robin slot
    const int lin  = blockIdx.x;
    const int wgid = (lin & 7) * WPX + (lin >> 3);
    const int ig   = wgid % NIG;            // i-group fastest: tile reuse in-XCD
    const int rem  = wgid / NIG;
    const int jtg  = rem & 3;
    const int b    = rem >> 2;

    const int jt0  = jtg * 1024;
    const int lane = threadIdx.x & 63;
    const int wv   = threadIdx.x >> 6;
    const int ib   = ig * 16 + wv * 4;

    const int jl = jt0 + lane * 4;          // span k at jl + 256*k
    const bool v0 = (jl + 0   < JT);        // JT%4==0: whole-float4 validity
    const bool v1 = (jl + 256 < JT);
    const bool v2 = (jl + 512 < JT);
    const bool v3 = (jl + 768 < JT);

    const float* yb = yhat + (size_t)b * CO * JT + jl;
    const float* lp = lhat + (size_t)b * CO * LHP + ib;

    v4f acc[4][4];                          // [row r][span k]
#pragma unroll
    for (int r = 0; r < 4; ++r)
#pragma unroll
        for (int k = 0; k < 4; ++k) acc[r][k] = (v4f)0.f;

#pragma unroll
    for (int c = 0; c < CO; ++c) {
        const float* yc = yb + c * JT;
        v4f y0 = v0 ? *(const v4f*)(yc + 0)   : (v4f)0.f;
        v4f y1 = v1 ? *(const v4f*)(yc + 256) : (v4f)0.f;
        v4f y2 = v2 ? *(const v4f*)(yc + 512) : (v4f)0.f;
        v4f y3 = v3 ? *(const v4f*)(yc + 768) : (v4f)0.f;
        v4f lt = *(const v4f*)(lp + c * LHP);   // same-addr-per-wave, L1 broadcast
#pragma unroll
        for (int r = 0; r < 4; ++r) {
            float lv = lt[r];
            acc[r][0] += lv * y0;
            acc[r][1] += lv * y1;
            acc[r][2] += lv * y2;
            acc[r][3] += lv * y3;
        }
    }

#pragma unroll
    for (int r = 0; r < 4; ++r) {
        int i = ib + r;
        if (i < NN) {
            float* op = out + ((size_t)b * NN + i) * JT + jl;
            if (v0) *(v4f*)(op + 0)   = acc[r][0];   // 4 adjacent 1KB wave-spans:
            if (v1) *(v4f*)(op + 256) = acc[r][1];   // 4KB sequential per row
            if (v2) *(v4f*)(op + 512) = acc[r][2];
            if (v3) *(v4f*)(op + 768) = acc[r][3];
        }
    }
}

extern "C" void kernel_launch(void* const* d_in, const int* in_sizes, int n_in,
                              void* d_out, int out_size, void* d_ws, size_t ws_size,
                              hipStream_t stream) {
    const float* x    = (const float*)d_in[0];
    const float* w    = (const float*)d_in[1];
    const float* bias = (const float*)d_in[2];
    float* out = (float*)d_out;

    float* ws   = (float*)d_ws;
    float* yhat = ws;                                  // B_*CO*JT  = 3,772,416 f
    float* lhat = yhat + (size_t)B_ * CO * JT;         // B_*CO*LHP =   327,680 f
    float* wt   = lhat + (size_t)B_ * CO * LHP;        // 3072 f    (~16.4 MB)

    repack_w_kernel<<<(CO * CIN * 3 + 255) / 256, 256, 0, stream>>>(w, wt);

    conv_norm_kernel<<<(B_ * JT) / 256, 256, 0, stream>>>(x, wt, bias, yhat, lhat);

    cos_kernel<<<NWG, 256, 0, stream>>>(yhat, lhat, out);
}

// Round 7
// 405.105 us; speedup vs baseline: 1.0621x; 1.0358x over previous
//
#include <hip/hip_runtime.h>

typedef float v4f __attribute__((ext_vector_type(4)));

#define B_   64
#define CIN  64
#define CO   16
#define NN   307
#define LL   12
#define JT   (NN * LL)   // 3684
#define LHP  320         // padded lhat row stride (16B-aligned float4 rows)

// cos tiling: block = 32 rows x 512 cols; wave = 8 rows x 512 cols
#define NRB  10                      // ceil(307/32)
#define NCB  8                       // ceil(3684/512)
#define NWG  (NRB * NCB * B_)        // 5120
#define WPX  (NWG / 8)               // 640 per XCD -> XCD k owns b in [8k,8k+8)

// conv: 921 blocks, padded to 928 for the XCD chunk map (skip wg>=921)
#define NCONV   ((B_ * JT) / 256)    // 921
#define NCONV_P 928
#define CPX     (NCONV_P / 8)        // 116

// ---------------------------------------------------------------------------
// Kernel 0: repack w [o][i][k] -> wt [i][k][o] (wave-uniform 16-float rows).
// ---------------------------------------------------------------------------
__global__ void repack_w_kernel(const float* __restrict__ w, float* __restrict__ wt) {
    int t = blockIdx.x * 256 + threadIdx.x;
    if (t < CO * CIN * 3) {
        int o = t & 15;
        int k = (t >> 4) % 3;
        int i = t / 48;
        wt[i * 48 + k * 16 + o] = w[(o * CIN + i) * 3 + k];
    }
}

// ---------------------------------------------------------------------------
// Kernel 1: conv(1x3, pad 1) + bias + channel-norm fold.
// XCD-chunked block remap so XCD k WRITES yhat for b ~ [8k, 8k+8) — the same
// XCD that cos will READ them on (local-L2 hits instead of L3).
// ---------------------------------------------------------------------------
__global__ __launch_bounds__(256) void conv_norm_kernel(
    const float* __restrict__ x, const float* __restrict__ wt,
    const float* __restrict__ bias, float* __restrict__ yhat,
    float* __restrict__ lhat) {
    int wg = (blockIdx.x & 7) * CPX + (blockIdx.x >> 3);
    if (wg >= NCONV) return;
    int tid = wg * 256 + threadIdx.x;           // exactly B_*JT work items
    int b   = tid / JT;
    int rem = tid - b * JT;                     // n*12 + l
    int n   = rem / LL;
    int l   = rem - n * LL;

    const float* xp = x + (size_t)b * CIN * JT + rem;

    float acc[CO];
#pragma unroll
    for (int o = 0; o < CO; ++o) acc[o] = bias[o];

    const int   offm = (l > 0) ? -1 : 0;
    const int   offp = (l < LL - 1) ? 1 : 0;
    const float mm   = (l > 0) ? 1.f : 0.f;
    const float mp   = (l < LL - 1) ? 1.f : 0.f;

#pragma unroll 4
    for (int i = 0; i < CIN; ++i) {
        const float* xr = xp + i * JT;
        float xm = xr[offm] * mm;
        float x0 = xr[0];
        float xq = xr[offp] * mp;
        const float* wr = wt + i * 48;   // wave-uniform -> s_load
#pragma unroll
        for (int o = 0; o < CO; ++o) {
            acc[o] += wr[o] * xm + wr[16 + o] * x0 + wr[32 + o] * xq;
        }
    }

    float ss = 0.f;
#pragma unroll
    for (int o = 0; o < CO; ++o) ss += acc[o] * acc[o];
    float inv = 1.f / fmaxf(sqrtf(ss), 1e-8f);

    float* yp = yhat + (size_t)b * CO * JT + rem;
#pragma unroll
    for (int o = 0; o < CO; ++o) yp[o * JT] = acc[o] * inv;

    if (l == LL - 1) {
        float* lp = lhat + (size_t)b * CO * LHP + n;
#pragma unroll
        for (int o = 0; o < CO; ++o) lp[o * LHP] = acc[o] * inv;
    }
}

// ---------------------------------------------------------------------------
// Kernel 2: out[b][i][jt] = sum_c lhat[b][c][i] * yhat[b][c][jt]
// VMEM-diet version: per thread 32 y-loads + 16 stores (3 VMEM per out-v4f,
// was 6). lhat slab (32 rows x 16 c = 2 KB) staged in LDS once per block;
// in-loop lhat reads are wave-uniform ds broadcasts (separate LDS pipe).
// Wave = 8 rows x 512 cols -> stores are 2KB-contiguous per row per wave.
// XCD-bijective swizzle matches conv's writer chunks (local-L2 y reads).
// ---------------------------------------------------------------------------
__global__ __launch_bounds__(256) void cos_kernel(
    const float* __restrict__ yhat, const float* __restrict__ lhat,
    float* __restrict__ out) {
    __shared__ float lsh[CO][32];            // [c][row-in-block], 2 KB

    const int wgid = (blockIdx.x & 7) * WPX + (blockIdx.x >> 3);
    const int rb   = wgid % NRB;             // row-block fastest: y-tile reuse
    const int rem  = wgid / NRB;
    const int cb   = rem & 7;
    const int b    = rem >> 3;

    const int i0  = rb * 32;
    const int jt0 = cb * 512;
    const int t   = threadIdx.x;

    // stage lhat slab: 512 floats, 2 per thread (reads stay inside LHP pad)
    {
        const float* lb = lhat + (size_t)b * CO * LHP + i0;
#pragma unroll
        for (int k = 0; k < 2; ++k) {
            int idx = t + k * 256;
            int c = idx >> 5, j = idx & 31;
            lsh[c][j] = lb[c * LHP + j];
        }
    }
    __syncthreads();

    const int lane = t & 63;
    const int wv   = t >> 6;
    const int wrow = wv * 8;                 // wave's first row within block
    const int jl   = jt0 + lane * 4;         // span A; span B at jl+256
    const bool vA  = (jl < JT);              // JT % 4 == 0
    const bool vB  = (jl + 256 < JT);

    const float* yb = yhat + (size_t)b * CO * JT + jl;

    v4f accA[8], accB[8];
#pragma unroll
    for (int r = 0; r < 8; ++r) { accA[r] = (v4f)0.f; accB[r] = (v4f)0.f; }

#pragma unroll
    for (int c = 0; c < CO; ++c) {
        const float* yc = yb + c * JT;
        v4f yA = vA ? *(const v4f*)(yc + 0)   : (v4f)0.f;
        v4f yB = vB ? *(const v4f*)(yc + 256) : (v4f)0.f;
        v4f l0 = *(const v4f*)&lsh[c][wrow];       // wave-uniform broadcast
        v4f l1 = *(const v4f*)&lsh[c][wrow + 4];
#pragma unroll
        for (int r = 0; r < 4; ++r) {
            accA[r]     += l0[r] * yA;
            accB[r]     += l0[r] * yB;
            accA[4 + r] += l1[r] * yA;
            accB[4 + r] += l1[r] * yB;
        }
    }

#pragma unroll
    for (int r = 0; r < 8; ++r) {
        int i = i0 + wrow + r;
        if (i < NN) {
            float* op = out + ((size_t)b * NN + i) * JT + jl;
            if (vA) *(v4f*)(op + 0)   = accA[r];
            if (vB) *(v4f*)(op + 256) = accB[r];
        }
    }
}

extern "C" void kernel_launch(void* const* d_in, const int* in_sizes, int n_in,
                              void* d_out, int out_size, void* d_ws, size_t ws_size,
                              hipStream_t stream) {
    const float* x    = (const float*)d_in[0];
    const float* w    = (const float*)d_in[1];
    const float* bias = (const float*)d_in[2];
    float* out = (float*)d_out;

    float* ws   = (float*)d_ws;
    float* yhat = ws;                                  // B_*CO*JT  = 3,772,416 f
    float* lhat = yhat + (size_t)B_ * CO * JT;         // B_*CO*LHP =   327,680 f
    float* wt   = lhat + (size_t)B_ * CO * LHP;        // 3072 f    (~16.4 MB)

    repack_w_kernel<<<(CO * CIN * 3 + 255) / 256, 256, 0, stream>>>(w, wt);

    conv_norm_kernel<<<NCONV_P, 256, 0, stream>>>(x, wt, bias, yhat, lhat);

    cos_kernel<<<NWG, 256, 0, stream>>>(yhat, lhat, out);
}